// Round 12
// baseline (5510.289 us; speedup 1.0000x reference)
//
#include <hip/hip_runtime.h>
#include <hip/hip_bf16.h>

#define TT 1000
#define HH 512
#define HH2 1024
#define DT_ 0.01f
// sqrt(2*DT*SIGMA_RECUR^2), sqrt(2*DT*SIGMA_INPUT^2)
#define PH_SCALE 7.0710678118654745e-4f
#define PI_SCALE 7.0710678118654745e-3f

typedef short s16x8 __attribute__((ext_vector_type(8)));
typedef float f32x4 __attribute__((ext_vector_type(4)));
typedef unsigned u32x4 __attribute__((ext_vector_type(4)));

#define SIGN32  0x80008000u
#define STRIP32 0x7fff7fffu

static __device__ __forceinline__ unsigned short bf16_bits(float f) {
    union { __hip_bfloat16 h; unsigned short u; } b; b.h = __float2bfloat16(f); return b.u;
}
// generation tag for h[t]: 2 bits, period 4; same-slot reuse distance 2 -> adjacent
// generations always differ. End-of-run slots hold tags 3/2 and 0xAA poison reads
// tag 3, while t=0/1 expect tag 0 -> stale data never satisfies a poll. (R6-R10.)
static __device__ __forceinline__ unsigned pat32(int t) {
    const unsigned tg = ((unsigned)t >> 1) & 3u;
    return ((tg & 1u) << 15) | ((tg & 2u) << 30);
}

// Persistent RNN, two-group ping-pong (latency hiding across independent
// recurrences). Grid: 32 blocks x 256 threads (4 waves). Block b serves TWO
// independent 16-row batch groups: A = rows [16*(b>>4)), B = A + 32 rows.
// 16 blocks per group (qb = b&15 -> 64-col slice; wave = 16x16 C tile).
// Schedule: MFMA A[t] -> publish A[t+1] -> stage B[t] -> barrier -> MFMA B[t]
// -> publish B[t+1] -> stage A[t+1] -> barrier -> ... Each group's publish
// gets a full opposite-phase (~MFMA+RTT) of propagation time before its
// consumers' stage issues -> round-1 tag success; L3 visibility is hidden.
// Protocol per group = R10 exactly: tag-in-data (sign bits of h>=0), publish
// fire-and-forget, stage-with-retry IS the readiness detection, skip-last-
// publish for replay safety, gen t staged before gen t+1 published (overwrite
// induction). LDS: 2 x 32 KB single-buffered; WAR covered by the alternating
// barriers (stage A[t+1] is separated from MFMA A[t] by the B-phase barrier).
__global__ __launch_bounds__(256, 1) void rnn_persistent(
    const float* __restrict__ inp, const float* __restrict__ hn,
    const float* __restrict__ x0g, const float* __restrict__ inhib,
    const float* __restrict__ ph, const float* __restrict__ pig,
    const float* __restrict__ s2s, const float* __restrict__ a2a,
    const float* __restrict__ a2s, const float* __restrict__ s2a,
    const float* __restrict__ iw,
    float* __restrict__ rnn_out, float* __restrict__ x_out,
    unsigned* __restrict__ hbuf)         // [2][64][512] u32 (packed tagged bf16 pairs)
{
    const int tid  = threadIdx.x;
    const int wid  = tid >> 6;
    const int lane = tid & 63;
    const int b    = blockIdx.x;         // 0..31
    const int qb   = b & 15;             // column-slice block within each group
    const int gA   = (b >> 4) * 16;      // group A rows base (0 or 16)
    const int gB   = gA + 32;            // group B rows base (32 or 48)
    const int l15  = lane & 15;
    const int lq   = lane >> 4;
    const int icol = (qb * 4 + wid) * 16 + l15;   // output column (= W row)

    __shared__ __align__(16) unsigned short hldsA[16 * 1024];  // 32 KB
    __shared__ __align__(16) unsigned short hldsB[16 * 1024];  // 32 KB

    // ---- publish h0 for BOTH groups FIRST ----
    {
        const unsigned p0 = pat32(0);
        #pragma unroll
        for (int gi = 0; gi < 2; ++gi) {
            const int gbase = gi ? gB : gA;
            float h0v[4];
            #pragma unroll
            for (int r = 0; r < 4; ++r)
                h0v[r] = hn[(size_t)(gbase + lq * 4 + r) * HH2 + icol];
            float prr[4];
            #pragma unroll
            for (int r = 0; r < 4; ++r) prr[r] = __shfl_xor(h0v[r], 1);
            if (!(l15 & 1)) {
                #pragma unroll
                for (int r = 0; r < 4; ++r) {
                    const unsigned val = (((unsigned)bf16_bits(h0v[r]) |
                                           ((unsigned)bf16_bits(prr[r]) << 16)) & STRIP32);
                    __hip_atomic_store(hbuf + (size_t)(gbase + lq * 4 + r) * 512 + (icol >> 1),
                                       val | p0, __ATOMIC_RELAXED, __HIP_MEMORY_SCOPE_AGENT);
                }
            }
        }
    }

    // ---- W fragments in registers (one-time, f32 -> bf16; shared by A and B) ----
    s16x8 wfr[32];
    #pragma unroll
    for (int kc = 0; kc < 32; ++kc) {
        const int j = kc * 32 + lq * 8;
        const float* src;
        if (icol < HH) src = (j < HH) ? (s2s + (size_t)icol * HH + j)
                                      : (a2s + (size_t)icol * HH + (j - HH));
        else           src = (j < HH) ? (s2a + (size_t)(icol - HH) * HH + j)
                                      : (a2a + (size_t)(icol - HH) * HH + (j - HH));
        const float4 f0 = *(const float4*)(src);
        const float4 f1 = *(const float4*)(src + 4);
        union { s16x8 vv; unsigned short us[8]; } u;
        u.us[0] = bf16_bits(f0.x); u.us[1] = bf16_bits(f0.y);
        u.us[2] = bf16_bits(f0.z); u.us[3] = bf16_bits(f0.w);
        u.us[4] = bf16_bits(f1.x); u.us[5] = bf16_bits(f1.y);
        u.us[6] = bf16_bits(f1.z); u.us[7] = bf16_bits(f1.w);
        wfr[kc] = u.vv;
    }

    // ---- per-group register-resident epilogue state ----
    const bool isStr = (icol < HH);
    float iw0 = 0.f, iw1 = 0.f, iw2 = 0.f, iw3 = 0.f;
    if (isStr) {
        iw0 = iw[icol]; iw1 = iw[HH2 + icol];
        iw2 = iw[2 * HH2 + icol]; iw3 = iw[3 * HH2 + icol];
    }
    float xrA[4], inhA[4], xrB[4], inhB[4];
    float4 ipfA[4], ipfB[4];
    #pragma unroll
    for (int r = 0; r < 4; ++r) {
        const int ba = gA + lq * 4 + r, bb = gB + lq * 4 + r;
        xrA[r]  = x0g[(size_t)ba * HH2 + icol];
        inhA[r] = inhib[(size_t)ba * HH2 + icol];
        ipfA[r] = *(const float4*)(inp + ((size_t)ba * TT + 0) * 4);
        xrB[r]  = x0g[(size_t)bb * HH2 + icol];
        inhB[r] = inhib[(size_t)bb * HH2 + icol];
        ipfB[r] = *(const float4*)(inp + ((size_t)bb * TT + 0) * 4);
    }
    float phv = ph[0], piv = pig[0];

    // ---- stage-with-retry of generation t (rows gbase..+16) into dst ----
    auto stage = [&](int t, int gbase, unsigned short* dst) {
        const unsigned* srcs = hbuf + (size_t)(t & 1) * 32768 + (size_t)gbase * 512;
        const unsigned p32 = pat32(t);
        u32x4 c[8];
        #pragma unroll
        for (int rd = 0; rd < 8; ++rd) {
            const int gch = tid + rd * 256;            // chunk id [0,2048)
            const int row = gch >> 7, c16 = gch & 127;
            const unsigned* p = srcs + row * 512 + c16 * 4;
            asm volatile("global_load_dwordx4 %0, %1, off sc0 sc1"
                         : "=v"(c[rd]) : "v"(p) : "memory");
        }
        asm volatile("s_waitcnt vmcnt(0)" ::: "memory");
        unsigned fm = 0u;
        #pragma unroll
        for (int rd = 0; rd < 8; ++rd) {
            const unsigned y = ((c[rd][0] ^ p32) | (c[rd][1] ^ p32) |
                                (c[rd][2] ^ p32) | (c[rd][3] ^ p32)) & SIGN32;
            if (y) fm |= 1u << rd;
        }
        while (fm) {
            #pragma unroll
            for (int rd = 0; rd < 8; ++rd) {
                if (fm & (1u << rd)) {
                    const int gch = tid + rd * 256;
                    const int row = gch >> 7, c16 = gch & 127;
                    const unsigned* p = srcs + row * 512 + c16 * 4;
                    asm volatile("global_load_dwordx4 %0, %1, off sc0 sc1"
                                 : "=v"(c[rd]) : "v"(p) : "memory");
                }
            }
            asm volatile("s_waitcnt vmcnt(0)" ::: "memory");
            #pragma unroll
            for (int rd = 0; rd < 8; ++rd) {
                if (fm & (1u << rd)) {
                    const unsigned y = ((c[rd][0] ^ p32) | (c[rd][1] ^ p32) |
                                        (c[rd][2] ^ p32) | (c[rd][3] ^ p32)) & SIGN32;
                    if (!y) fm &= ~(1u << rd);
                }
            }
        }
        #pragma unroll
        for (int rd = 0; rd < 8; ++rd) {
            const int gch = tid + rd * 256;
            const int row = gch >> 7, c16 = gch & 127;
            u32x4 s;
            s[0] = c[rd][0] & STRIP32; s[1] = c[rd][1] & STRIP32;
            s[2] = c[rd][2] & STRIP32; s[3] = c[rd][3] & STRIP32;
            *(u32x4*)((char*)dst + row * 2048 + ((c16 ^ (row & 7)) * 16)) = s;
        }
    };

    // MFMA + epilogue + publish + history + prefetch for one group's step t
    auto phase = [&](int t, int gbase, const unsigned short* buf,
                     float* xr, const float* inh, float4* ipf,
                     float phs, float pis) {
        f32x4 acc[4] = {{0,0,0,0},{0,0,0,0},{0,0,0,0},{0,0,0,0}};
        const char* arow = (const char*)buf + l15 * 2048;
        #pragma unroll
        for (int kc = 0; kc < 32; ++kc) {
            s16x8 a0 = *(const s16x8*)(arow + (((kc << 2 | lq) ^ (l15 & 7)) * 16));
            acc[kc & 3] = __builtin_amdgcn_mfma_f32_16x16x32_bf16(a0, wfr[kc], acc[kc & 3], 0, 0, 0);
        }
        float xn_[4], hv_[4];
        #pragma unroll
        for (int r = 0; r < 4; ++r) {
            const float rec = acc[0][r] + acc[1][r] + acc[2][r] + acc[3][r];
            float drive = 0.f;
            if (isStr) drive = (ipf[r].x + pis) * iw0 + (ipf[r].y + pis) * iw1 +
                               (ipf[r].z + pis) * iw2 + (ipf[r].w + pis) * iw3;
            const float xp = xr[r];
            const float xn = xp + DT_ * (-xp + rec + drive + inh[r]) + phs;
            const float hv = fmaxf(xn, 0.f);
            xr[r] = xn; xn_[r] = xn; hv_[r] = hv;
        }
        // publish h[t+1] tagged, fire-and-forget (skip last: replay safety)
        if (t + 1 < TT) {
            unsigned* nxt = hbuf + (size_t)((t + 1) & 1) * 32768;
            const unsigned pn = pat32(t + 1);
            float prr[4];
            #pragma unroll
            for (int r = 0; r < 4; ++r) prr[r] = __shfl_xor(hv_[r], 1);
            if (!(l15 & 1)) {
                #pragma unroll
                for (int r = 0; r < 4; ++r) {
                    const unsigned val = (((unsigned)bf16_bits(hv_[r]) |
                                           ((unsigned)bf16_bits(prr[r]) << 16)) & STRIP32);
                    __hip_atomic_store(nxt + (size_t)(gbase + lq * 4 + r) * 512 + (icol >> 1),
                                       val | pn, __ATOMIC_RELAXED, __HIP_MEMORY_SCOPE_AGENT);
                }
            }
        }
        // history stores (plain, L2-ack; drain overlaps next stage's vmcnt)
        #pragma unroll
        for (int r = 0; r < 4; ++r) {
            const int bi = gbase + lq * 4 + r;
            const size_t o = ((size_t)bi * TT + t) * HH2 + icol;
            rnn_out[o] = hv_[r];
            x_out[o]   = xn_[r];
        }
        // next-step input prefetch
        const int tn = (t + 1 < TT) ? (t + 1) : t;
        #pragma unroll
        for (int r = 0; r < 4; ++r)
            ipf[r] = *(const float4*)(inp + ((size_t)(gbase + lq * 4 + r) * TT + tn) * 4);
    };

    // prologue: stage A[0]
    stage(0, gA, hldsA);
    __syncthreads();

    #pragma unroll 1
    for (int t = 0; t < TT; ++t) {
        const float phs = PH_SCALE * phv;
        const float pis = PI_SCALE * piv;
        const int tn = (t + 1 < TT) ? (t + 1) : t;

        // ---- A phase: compute A[t]; then stage B[t] (B publishes are a full
        //      phase old -> visible -> round-1 success) ----
        phase(t, gA, hldsA, xrA, inhA, ipfA, phs, pis);
        stage(t, gB, hldsB);
        __syncthreads();

        // ---- B phase: compute B[t]; then stage A[t+1] (A publishes aged one
        //      full phase) ----
        phase(t, gB, hldsB, xrB, inhB, ipfB, phs, pis);
        phv = ph[tn]; piv = pig[tn];
        if (t + 1 < TT) stage(t + 1, gA, hldsA);
        __syncthreads();
    }
}

// ---------------- fc1: out[b,t] = dot(rnn_out[b,t,512:1024], fc1_w[512:1024]) + fc1_b ----------------
__global__ __launch_bounds__(256) void fc1_kernel(
    const float* __restrict__ rnn_out, const float* __restrict__ fc1_w,
    const float* __restrict__ fc1_b, float* __restrict__ out)
{
    const int wid = blockIdx.x * 4 + (threadIdx.x >> 6);  // [0, 64000)
    const int lane = threadIdx.x & 63;
    const float* p = rnn_out + (size_t)wid * HH2 + HH + lane * 8;
    const float* w = fc1_w + HH + lane * 8;
    f32x4 v0 = *(const f32x4*)(p);
    f32x4 v1 = *(const f32x4*)(p + 4);
    f32x4 w0 = *(const f32x4*)(w);
    f32x4 w1 = *(const f32x4*)(w + 4);
    float s = v0[0]*w0[0] + v0[1]*w0[1] + v0[2]*w0[2] + v0[3]*w0[3]
            + v1[0]*w1[0] + v1[1]*w1[1] + v1[2]*w1[2] + v1[3]*w1[3];
    #pragma unroll
    for (int off = 32; off; off >>= 1) s += __shfl_xor(s, off);
    if (lane == 0) out[wid] = s + fc1_b[0];
}

// ---------------- last-state extraction ----------------
__global__ __launch_bounds__(256) void last_kernel(
    const float* __restrict__ rnn_out, const float* __restrict__ x_out,
    float* __restrict__ hn_last, float* __restrict__ x_last)
{
    const int idx = blockIdx.x * 256 + threadIdx.x;  // [0, 65536)
    const int b = idx >> 10;
    const int i = idx & 1023;
    const size_t o = ((size_t)b * TT + (TT - 1)) * HH2 + i;
    hn_last[idx] = rnn_out[o];
    x_last[idx]  = x_out[o];
}

extern "C" void kernel_launch(void* const* d_in, const int* in_sizes, int n_in,
                              void* d_out, int out_size, void* d_ws, size_t ws_size,
                              hipStream_t stream) {
    const float* inp   = (const float*)d_in[0];   // [64,1000,4]
    const float* hn    = (const float*)d_in[1];   // [1,64,1024]
    const float* x     = (const float*)d_in[2];   // [1,64,1024]
    const float* inhib = (const float*)d_in[3];   // [64,1024]
    const float* ph    = (const float*)d_in[4];   // [1000]
    const float* pi    = (const float*)d_in[5];   // [1000]
    const float* s2s   = (const float*)d_in[6];   // [512,512]
    const float* a2a   = (const float*)d_in[7];
    const float* a2s   = (const float*)d_in[8];
    const float* s2a   = (const float*)d_in[9];
    const float* iw    = (const float*)d_in[10];  // [4,1024]
    const float* fw    = (const float*)d_in[11];  // [1,1024]
    const float* fb    = (const float*)d_in[12];  // [1]

    // Output tuple layout (floats): out | hn_last | rnn_out | x_last | x_out
    float* out     = (float*)d_out;               // 64000
    float* hn_last = out + 64000;                 // 65536
    float* rnn_out = out + 129536;                // 65,536,000
    float* x_last  = out + 65665536;              // 65536
    float* x_out   = out + 65731072;              // 65,536,000

    // Workspace: hbuf [2][64][512] u32 = 256 KB. No init needed: generation tags
    // self-disambiguate against both 0xAA poison and previous-replay residue.
    unsigned* hbuf = (unsigned*)d_ws;

    rnn_persistent<<<32, 256, 0, stream>>>(inp, hn, x, inhib, ph, pi,
                                           s2s, a2a, a2s, s2a, iw,
                                           rnn_out, x_out, hbuf);
    fc1_kernel<<<16000, 256, 0, stream>>>(rnn_out, fw, fb, out);
    last_kernel<<<256, 256, 0, stream>>>(rnn_out, x_out, hn_last, x_last);
}

// Round 13
// 2404.283 us; speedup vs baseline: 2.2919x; 2.2919x over previous
//
#include <hip/hip_runtime.h>
#include <hip/hip_bf16.h>

#define TT 1000
#define HH 512
#define HH2 1024
#define DT_ 0.01f
// sqrt(2*DT*SIGMA_RECUR^2), sqrt(2*DT*SIGMA_INPUT^2)
#define PH_SCALE 7.0710678118654745e-4f
#define PI_SCALE 7.0710678118654745e-3f

typedef short s16x8 __attribute__((ext_vector_type(8)));
typedef float f32x4 __attribute__((ext_vector_type(4)));
typedef unsigned u32x4 __attribute__((ext_vector_type(4)));

#define SIGN32  0x80008000u
#define STRIP32 0x7fff7fffu

static __device__ __forceinline__ unsigned short bf16_bits(float f) {
    union { __hip_bfloat16 h; unsigned short u; } b; b.h = __float2bfloat16(f); return b.u;
}
// generation tag for h[t]: 2 bits, period 4; same-slot reuse distance 2 -> adjacent
// generations always differ. End-of-run slots hold tags 3/2 and 0xAA poison reads
// tag 3, while t=0/1 expect tag 0 -> stale data never satisfies a poll. (R6-R10.)
static __device__ __forceinline__ unsigned pat32(int t) {
    const unsigned tg = ((unsigned)t >> 1) & 3u;
    return ((tg & 1u) << 15) | ((tg & 2u) << 30);
}

// Persistent RNN — R10 skeleton, slimmed chain (8-row groups).
// Grid: 128 blocks x 256 threads (4 waves). Group = 16 blocks owning batch rows
// [8g, 8g+8), g = b>>4 (8 groups); block = 64 cols (4 waves x 16). Wave computes
// a 16x16 C tile with M=8 duplication (A row = l15&7; C rows 8-15 are discarded
// duplicates; owner lanes lq<2 hold batch rows lq*4+r). LDS A-reads for dup rows
// are same-address broadcasts (free) -> per-wave LDS traffic 16 KB (was 32 KB).
// Protocol unchanged from R10: tag-in-data (sign bits of h>=0), publish fire-and-
// forget, stage-with-retry IS the readiness detection, plain history stores whose
// L2-acks ride under the stage vmcnt, skip-last-publish replay safety, dbuf LDS,
// ONE __syncthreads per step. Retry spin carries a tiny FMA burn (DVFS nudge).
__global__ __launch_bounds__(256, 1) void rnn_persistent(
    const float* __restrict__ inp, const float* __restrict__ hn,
    const float* __restrict__ x0g, const float* __restrict__ inhib,
    const float* __restrict__ ph, const float* __restrict__ pig,
    const float* __restrict__ s2s, const float* __restrict__ a2a,
    const float* __restrict__ a2s, const float* __restrict__ s2a,
    const float* __restrict__ iw,
    float* __restrict__ rnn_out, float* __restrict__ x_out,
    unsigned* __restrict__ hbuf)         // [2][64][512] u32 (packed tagged bf16 pairs)
{
    const int tid  = threadIdx.x;
    const int wid  = tid >> 6;
    const int lane = tid & 63;
    const int b    = blockIdx.x;         // 0..127
    const int g    = b >> 4;             // row group (batch rows 8g..8g+8)
    const int qb   = b & 15;             // block within group (64-col slice)
    const int l15  = lane & 15;
    const int lq   = lane >> 4;
    const int r8   = l15 & 7;            // A-fragment batch-row offset
    const int g8   = g * 8;
    const int icol = (qb * 4 + wid) * 16 + l15;   // output column (= W row)
    const bool owner = (lq < 2);                  // holds batch rows lq*4+r
    const int rowbase = g8 + (lq & 1) * 4;        // clamped row base for loads

    __shared__ __align__(16) unsigned short hlds[2][8 * 1024];  // 2 x 16 KB

    // ---- publish h0 FIRST (tag gen 0) ----
    {
        float h0v[4];
        #pragma unroll
        for (int r = 0; r < 4; ++r)
            h0v[r] = hn[(size_t)(rowbase + r) * HH2 + icol];
        float prr[4];
        #pragma unroll
        for (int r = 0; r < 4; ++r) prr[r] = __shfl_xor(h0v[r], 1);
        if (owner && !(l15 & 1)) {
            const unsigned p0 = pat32(0);
            #pragma unroll
            for (int r = 0; r < 4; ++r) {
                const unsigned val = (((unsigned)bf16_bits(h0v[r]) |
                                       ((unsigned)bf16_bits(prr[r]) << 16)) & STRIP32);
                __hip_atomic_store(hbuf + (size_t)(g8 + lq * 4 + r) * 512 + (icol >> 1),
                                   val | p0, __ATOMIC_RELAXED, __HIP_MEMORY_SCOPE_AGENT);
            }
        }
    }

    // ---- W fragments in registers (one-time, f32 -> bf16) ----
    s16x8 wfr[32];
    #pragma unroll
    for (int kc = 0; kc < 32; ++kc) {
        const int j = kc * 32 + lq * 8;
        const float* src;
        if (icol < HH) src = (j < HH) ? (s2s + (size_t)icol * HH + j)
                                      : (a2s + (size_t)icol * HH + (j - HH));
        else           src = (j < HH) ? (s2a + (size_t)(icol - HH) * HH + j)
                                      : (a2a + (size_t)(icol - HH) * HH + (j - HH));
        const float4 f0 = *(const float4*)(src);
        const float4 f1 = *(const float4*)(src + 4);
        union { s16x8 vv; unsigned short us[8]; } u;
        u.us[0] = bf16_bits(f0.x); u.us[1] = bf16_bits(f0.y);
        u.us[2] = bf16_bits(f0.z); u.us[3] = bf16_bits(f0.w);
        u.us[4] = bf16_bits(f1.x); u.us[5] = bf16_bits(f1.y);
        u.us[6] = bf16_bits(f1.z); u.us[7] = bf16_bits(f1.w);
        wfr[kc] = u.vv;
    }

    // ---- register-resident epilogue state (clamped rows; masked on use) ----
    const bool isStr = (icol < HH);
    float iw0 = 0.f, iw1 = 0.f, iw2 = 0.f, iw3 = 0.f;
    if (isStr) {
        iw0 = iw[icol]; iw1 = iw[HH2 + icol];
        iw2 = iw[2 * HH2 + icol]; iw3 = iw[3 * HH2 + icol];
    }
    float xr[4], inh[4];
    float4 ipf[4];
    #pragma unroll
    for (int r = 0; r < 4; ++r) {
        const int bi = rowbase + r;
        xr[r]  = x0g[(size_t)bi * HH2 + icol];
        inh[r] = inhib[(size_t)bi * HH2 + icol];
        ipf[r] = *(const float4*)(inp + ((size_t)bi * TT + 0) * 4);
    }
    float phv = ph[0], piv = pig[0];

    // ---- stage-with-retry of generation t into hlds[t&1] (poll IS the stage) ----
    auto stage = [&](int t) {
        const unsigned* srcs = hbuf + (size_t)(t & 1) * 32768 + (size_t)g8 * 512;
        char* dst = (char*)hlds[t & 1];
        const unsigned p32 = pat32(t);
        u32x4 c[4];
        #pragma unroll
        for (int rd = 0; rd < 4; ++rd) {
            const int gch = tid + rd * 256;            // chunk id [0,1024)
            const int row = gch >> 7, c16 = gch & 127;
            const unsigned* p = srcs + row * 512 + c16 * 4;
            asm volatile("global_load_dwordx4 %0, %1, off sc0 sc1"
                         : "=v"(c[rd]) : "v"(p) : "memory");
        }
        asm volatile("s_waitcnt vmcnt(0)" ::: "memory");   // also drains publish+history
        unsigned fm = 0u;
        #pragma unroll
        for (int rd = 0; rd < 4; ++rd) {
            const unsigned y = ((c[rd][0] ^ p32) | (c[rd][1] ^ p32) |
                                (c[rd][2] ^ p32) | (c[rd][3] ^ p32)) & SIGN32;
            if (y) fm |= 1u << rd;
        }
        float burn = (float)tid;
        while (fm) {
            #pragma unroll
            for (int rd = 0; rd < 4; ++rd) {
                if (fm & (1u << rd)) {
                    const int gch = tid + rd * 256;
                    const int row = gch >> 7, c16 = gch & 127;
                    const unsigned* p = srcs + row * 512 + c16 * 4;
                    asm volatile("global_load_dwordx4 %0, %1, off sc0 sc1"
                                 : "=v"(c[rd]) : "v"(p) : "memory");
                }
            }
            // small VALU burn while loads are in flight (keeps DVFS up; ~16 cyc)
            #pragma unroll
            for (int z = 0; z < 8; ++z) burn = fmaf(burn, 1.000001f, 0.5f);
            asm volatile("" :: "v"(burn));
            asm volatile("s_waitcnt vmcnt(0)" ::: "memory");
            #pragma unroll
            for (int rd = 0; rd < 4; ++rd) {
                if (fm & (1u << rd)) {
                    const unsigned y = ((c[rd][0] ^ p32) | (c[rd][1] ^ p32) |
                                        (c[rd][2] ^ p32) | (c[rd][3] ^ p32)) & SIGN32;
                    if (!y) fm &= ~(1u << rd);
                }
            }
        }
        #pragma unroll
        for (int rd = 0; rd < 4; ++rd) {
            const int gch = tid + rd * 256;
            const int row = gch >> 7, c16 = gch & 127;
            u32x4 s;
            s[0] = c[rd][0] & STRIP32; s[1] = c[rd][1] & STRIP32;
            s[2] = c[rd][2] & STRIP32; s[3] = c[rd][3] & STRIP32;
            *(u32x4*)(dst + row * 2048 + ((c16 ^ row) * 16)) = s;
        }
    };

    // prologue: stage h[0], barrier
    stage(0);
    __syncthreads();

    #pragma unroll 1
    for (int t = 0; t < TT; ++t) {
        // ---- MFMA: A rows r8 (M=8 dup), col icol, K=1024 from swizzled LDS ----
        f32x4 acc[4] = {{0,0,0,0},{0,0,0,0},{0,0,0,0},{0,0,0,0}};
        const char* arow = (const char*)hlds[t & 1] + r8 * 2048;
        #pragma unroll
        for (int kc = 0; kc < 32; ++kc) {
            s16x8 a0 = *(const s16x8*)(arow + (((kc << 2 | lq) ^ r8) * 16));
            acc[kc & 3] = __builtin_amdgcn_mfma_f32_16x16x32_bf16(a0, wfr[kc], acc[kc & 3], 0, 0, 0);
        }

        // ---- epilogue (valid on owner lanes: batch rows lq*4+r) ----
        const float phs = PH_SCALE * phv;
        const float pis = PI_SCALE * piv;
        float xn_[4], hv_[4];
        #pragma unroll
        for (int r = 0; r < 4; ++r) {
            const float rec = acc[0][r] + acc[1][r] + acc[2][r] + acc[3][r];
            float drive = 0.f;
            if (isStr) drive = (ipf[r].x + pis) * iw0 + (ipf[r].y + pis) * iw1 +
                               (ipf[r].z + pis) * iw2 + (ipf[r].w + pis) * iw3;
            const float xp = xr[r];
            const float xn = xp + DT_ * (-xp + rec + drive + inh[r]) + phs;
            const float hv = fmaxf(xn, 0.f);
            xr[r] = xn; xn_[r] = xn; hv_[r] = hv;
        }

        // ---- publish h[t+1] tagged, fire-and-forget (skip last: replay safety) ----
        if (t + 1 < TT) {
            unsigned* nxt = hbuf + (size_t)((t + 1) & 1) * 32768;
            const unsigned pn = pat32(t + 1);
            float prr[4];
            #pragma unroll
            for (int r = 0; r < 4; ++r) prr[r] = __shfl_xor(hv_[r], 1);
            if (owner && !(l15 & 1)) {
                #pragma unroll
                for (int r = 0; r < 4; ++r) {
                    const unsigned val = (((unsigned)bf16_bits(hv_[r]) |
                                           ((unsigned)bf16_bits(prr[r]) << 16)) & STRIP32);
                    __hip_atomic_store(nxt + (size_t)(g8 + lq * 4 + r) * 512 + (icol >> 1),
                                       val | pn, __ATOMIC_RELAXED, __HIP_MEMORY_SCOPE_AGENT);
                }
            }
        }

        // ---- history stores: plain (L2-ack); acks ride under stage's vmcnt(0) ----
        if (owner) {
            #pragma unroll
            for (int r = 0; r < 4; ++r) {
                const int bi = g8 + lq * 4 + r;
                const size_t o = ((size_t)bi * TT + t) * HH2 + icol;
                rnn_out[o] = hv_[r];
                x_out[o]   = xn_[r];
            }
        }

        // ---- next-step input prefetch (clamped rows) ----
        const int tn = (t + 1 < TT) ? (t + 1) : t;
        #pragma unroll
        for (int r = 0; r < 4; ++r)
            ipf[r] = *(const float4*)(inp + ((size_t)(rowbase + r) * TT + tn) * 4);
        phv = ph[tn]; piv = pig[tn];

        // ---- stage h[t+1] (poll+load combined), then the ONE barrier ----
        if (t + 1 < TT) stage(t + 1);
        __syncthreads();
    }
}

// ---------------- fc1: out[b,t] = dot(rnn_out[b,t,512:1024], fc1_w[512:1024]) + fc1_b ----------------
__global__ __launch_bounds__(256) void fc1_kernel(
    const float* __restrict__ rnn_out, const float* __restrict__ fc1_w,
    const float* __restrict__ fc1_b, float* __restrict__ out)
{
    const int wid = blockIdx.x * 4 + (threadIdx.x >> 6);  // [0, 64000)
    const int lane = threadIdx.x & 63;
    const float* p = rnn_out + (size_t)wid * HH2 + HH + lane * 8;
    const float* w = fc1_w + HH + lane * 8;
    f32x4 v0 = *(const f32x4*)(p);
    f32x4 v1 = *(const f32x4*)(p + 4);
    f32x4 w0 = *(const f32x4*)(w);
    f32x4 w1 = *(const f32x4*)(w + 4);
    float s = v0[0]*w0[0] + v0[1]*w0[1] + v0[2]*w0[2] + v0[3]*w0[3]
            + v1[0]*w1[0] + v1[1]*w1[1] + v1[2]*w1[2] + v1[3]*w1[3];
    #pragma unroll
    for (int off = 32; off; off >>= 1) s += __shfl_xor(s, off);
    if (lane == 0) out[wid] = s + fc1_b[0];
}

// ---------------- last-state extraction ----------------
__global__ __launch_bounds__(256) void last_kernel(
    const float* __restrict__ rnn_out, const float* __restrict__ x_out,
    float* __restrict__ hn_last, float* __restrict__ x_last)
{
    const int idx = blockIdx.x * 256 + threadIdx.x;  // [0, 65536)
    const int b = idx >> 10;
    const int i = idx & 1023;
    const size_t o = ((size_t)b * TT + (TT - 1)) * HH2 + i;
    hn_last[idx] = rnn_out[o];
    x_last[idx]  = x_out[o];
}

extern "C" void kernel_launch(void* const* d_in, const int* in_sizes, int n_in,
                              void* d_out, int out_size, void* d_ws, size_t ws_size,
                              hipStream_t stream) {
    const float* inp   = (const float*)d_in[0];   // [64,1000,4]
    const float* hn    = (const float*)d_in[1];   // [1,64,1024]
    const float* x     = (const float*)d_in[2];   // [1,64,1024]
    const float* inhib = (const float*)d_in[3];   // [64,1024]
    const float* ph    = (const float*)d_in[4];   // [1000]
    const float* pi    = (const float*)d_in[5];   // [1000]
    const float* s2s   = (const float*)d_in[6];   // [512,512]
    const float* a2a   = (const float*)d_in[7];
    const float* a2s   = (const float*)d_in[8];
    const float* s2a   = (const float*)d_in[9];
    const float* iw    = (const float*)d_in[10];  // [4,1024]
    const float* fw    = (const float*)d_in[11];  // [1,1024]
    const float* fb    = (const float*)d_in[12];  // [1]

    // Output tuple layout (floats): out | hn_last | rnn_out | x_last | x_out
    float* out     = (float*)d_out;               // 64000
    float* hn_last = out + 64000;                 // 65536
    float* rnn_out = out + 129536;                // 65,536,000
    float* x_last  = out + 65665536;              // 65536
    float* x_out   = out + 65731072;              // 65,536,000

    // Workspace: hbuf [2][64][512] u32 = 256 KB. No init needed: generation tags
    // self-disambiguate against both 0xAA poison and previous-replay residue.
    unsigned* hbuf = (unsigned*)d_ws;

    rnn_persistent<<<128, 256, 0, stream>>>(inp, hn, x, inhib, ph, pi,
                                            s2s, a2a, a2s, s2a, iw,
                                            rnn_out, x_out, hbuf);
    fc1_kernel<<<16000, 256, 0, stream>>>(rnn_out, fw, fb, out);
    last_kernel<<<256, 256, 0, stream>>>(rnn_out, x_out, hn_last, x_last);
}

// Round 14
// 2118.629 us; speedup vs baseline: 2.6009x; 1.1348x over previous
//
#include <hip/hip_runtime.h>
#include <hip/hip_bf16.h>

#define TT 1000
#define HH 512
#define HH2 1024
#define DT_ 0.01f
// sqrt(2*DT*SIGMA_RECUR^2), sqrt(2*DT*SIGMA_INPUT^2)
#define PH_SCALE 7.0710678118654745e-4f
#define PI_SCALE 7.0710678118654745e-3f

typedef short s16x8 __attribute__((ext_vector_type(8)));
typedef float f32x4 __attribute__((ext_vector_type(4)));
typedef unsigned u32x4 __attribute__((ext_vector_type(4)));

#define SIGN32  0x80008000u
#define STRIP32 0x7fff7fffu

static __device__ __forceinline__ unsigned short bf16_bits(float f) {
    union { __hip_bfloat16 h; unsigned short u; } b; b.h = __float2bfloat16(f); return b.u;
}
// generation tag for h[t]: 2 bits, period 4; same-slot reuse distance 2 -> adjacent
// generations always differ. End-of-run slots hold tags 3/2 and 0xAA poison reads
// tag 3, while t=0/1 expect tag 0 -> stale data never satisfies a poll. (R6-R13.)
static __device__ __forceinline__ unsigned pat32(int t) {
    const unsigned tg = ((unsigned)t >> 1) & 3u;
    return ((tg & 1u) << 15) | ((tg & 2u) << 30);
}

// Persistent RNN — R13 structure with 4-row groups (all 256 CUs busy).
// Grid: 256 blocks x 256 threads (4 waves). Group = 16 blocks owning batch rows
// [4g, 4g+4), g = b>>4 (16 groups); block = 64 cols (4 waves x 16). Wave computes
// a 16x16 C tile with M=4 duplication (A row = l15&3; C rows 4-15 are discarded
// duplicates; owner lanes lq==0 hold batch rows r=0..3). LDS A-reads for dup rows
// are same-address broadcasts (free).
// Protocol unchanged from R10/R13: tag-in-data (sign bits of h>=0), publish fire-
// and-forget, stage-with-retry IS the readiness detection (now write-on-pass so
// the LDS tail overlaps straggler retries), plain history stores whose L2-acks
// ride under the stage vmcnt, skip-last-publish replay safety, dbuf LDS, ONE
// __syncthreads per step, FMA burn in the retry spin (DVFS).
__global__ __launch_bounds__(256, 1) void rnn_persistent(
    const float* __restrict__ inp, const float* __restrict__ hn,
    const float* __restrict__ x0g, const float* __restrict__ inhib,
    const float* __restrict__ ph, const float* __restrict__ pig,
    const float* __restrict__ s2s, const float* __restrict__ a2a,
    const float* __restrict__ a2s, const float* __restrict__ s2a,
    const float* __restrict__ iw,
    float* __restrict__ rnn_out, float* __restrict__ x_out,
    unsigned* __restrict__ hbuf)         // [2][64][512] u32 (packed tagged bf16 pairs)
{
    const int tid  = threadIdx.x;
    const int wid  = tid >> 6;
    const int lane = tid & 63;
    const int b    = blockIdx.x;         // 0..255
    const int g    = b >> 4;             // row group (batch rows 4g..4g+4)
    const int qb   = b & 15;             // block within group (64-col slice)
    const int l15  = lane & 15;
    const int lq   = lane >> 4;
    const int r4   = l15 & 3;            // A-fragment batch-row offset (M=4 dup)
    const int g4   = g * 4;
    const int icol = (qb * 4 + wid) * 16 + l15;   // output column (= W row)
    const bool owner = (lq == 0);                 // holds batch rows r=0..3

    __shared__ __align__(16) unsigned short hlds[2][4 * 1024];  // 2 x 8 KB

    // ---- publish h0 FIRST (tag gen 0) ----
    {
        float h0v[4];
        #pragma unroll
        for (int r = 0; r < 4; ++r)
            h0v[r] = hn[(size_t)(g4 + r) * HH2 + icol];
        float prr[4];
        #pragma unroll
        for (int r = 0; r < 4; ++r) prr[r] = __shfl_xor(h0v[r], 1);
        if (owner && !(l15 & 1)) {
            const unsigned p0 = pat32(0);
            #pragma unroll
            for (int r = 0; r < 4; ++r) {
                const unsigned val = (((unsigned)bf16_bits(h0v[r]) |
                                       ((unsigned)bf16_bits(prr[r]) << 16)) & STRIP32);
                __hip_atomic_store(hbuf + (size_t)(g4 + r) * 512 + (icol >> 1),
                                   val | p0, __ATOMIC_RELAXED, __HIP_MEMORY_SCOPE_AGENT);
            }
        }
    }

    // ---- W fragments in registers (one-time, f32 -> bf16) ----
    s16x8 wfr[32];
    #pragma unroll
    for (int kc = 0; kc < 32; ++kc) {
        const int j = kc * 32 + lq * 8;
        const float* src;
        if (icol < HH) src = (j < HH) ? (s2s + (size_t)icol * HH + j)
                                      : (a2s + (size_t)icol * HH + (j - HH));
        else           src = (j < HH) ? (s2a + (size_t)(icol - HH) * HH + j)
                                      : (a2a + (size_t)(icol - HH) * HH + (j - HH));
        const float4 f0 = *(const float4*)(src);
        const float4 f1 = *(const float4*)(src + 4);
        union { s16x8 vv; unsigned short us[8]; } u;
        u.us[0] = bf16_bits(f0.x); u.us[1] = bf16_bits(f0.y);
        u.us[2] = bf16_bits(f0.z); u.us[3] = bf16_bits(f0.w);
        u.us[4] = bf16_bits(f1.x); u.us[5] = bf16_bits(f1.y);
        u.us[6] = bf16_bits(f1.z); u.us[7] = bf16_bits(f1.w);
        wfr[kc] = u.vv;
    }

    // ---- register-resident epilogue state (rows g4..g4+3, uniform across lq) ----
    const bool isStr = (icol < HH);
    float iw0 = 0.f, iw1 = 0.f, iw2 = 0.f, iw3 = 0.f;
    if (isStr) {
        iw0 = iw[icol]; iw1 = iw[HH2 + icol];
        iw2 = iw[2 * HH2 + icol]; iw3 = iw[3 * HH2 + icol];
    }
    float xr[4], inh[4];
    float4 ipf[4];
    #pragma unroll
    for (int r = 0; r < 4; ++r) {
        const int bi = g4 + r;
        xr[r]  = x0g[(size_t)bi * HH2 + icol];
        inh[r] = inhib[(size_t)bi * HH2 + icol];
        ipf[r] = *(const float4*)(inp + ((size_t)bi * TT + 0) * 4);
    }
    float phv = ph[0], piv = pig[0];

    // ---- stage-with-retry of generation t into hlds[t&1] (poll IS the stage;
    //      chunks written to LDS the moment their tag matches) ----
    auto stage = [&](int t) {
        const unsigned* srcs = hbuf + (size_t)(t & 1) * 32768 + (size_t)g4 * 512;
        char* dst = (char*)hlds[t & 1];
        const unsigned p32 = pat32(t);
        const int row0 = tid >> 7,         c160 = tid & 127;
        const int row1 = (tid + 256) >> 7, c161 = tid & 127;   // rows 0/1 then 2/3
        const unsigned* p0 = srcs + row0 * 512 + c160 * 4;
        const unsigned* p1 = srcs + row1 * 512 + c161 * 4;
        char* d0 = dst + row0 * 2048 + ((c160 ^ row0) * 16);
        char* d1 = dst + row1 * 2048 + ((c161 ^ row1) * 16);
        u32x4 c0, c1;
        asm volatile("global_load_dwordx4 %0, %1, off sc0 sc1" : "=v"(c0) : "v"(p0) : "memory");
        asm volatile("global_load_dwordx4 %0, %1, off sc0 sc1" : "=v"(c1) : "v"(p1) : "memory");
        asm volatile("s_waitcnt vmcnt(0)" ::: "memory");   // also drains publish+history
        bool f0 = (((c0[0] ^ p32) | (c0[1] ^ p32) | (c0[2] ^ p32) | (c0[3] ^ p32)) & SIGN32) != 0u;
        bool f1 = (((c1[0] ^ p32) | (c1[1] ^ p32) | (c1[2] ^ p32) | (c1[3] ^ p32)) & SIGN32) != 0u;
        if (!f0) { u32x4 s = {c0[0] & STRIP32, c0[1] & STRIP32, c0[2] & STRIP32, c0[3] & STRIP32};
                   *(u32x4*)d0 = s; }
        if (!f1) { u32x4 s = {c1[0] & STRIP32, c1[1] & STRIP32, c1[2] & STRIP32, c1[3] & STRIP32};
                   *(u32x4*)d1 = s; }
        float burn = (float)tid;
        while (f0 || f1) {
            if (f0) asm volatile("global_load_dwordx4 %0, %1, off sc0 sc1" : "=v"(c0) : "v"(p0) : "memory");
            if (f1) asm volatile("global_load_dwordx4 %0, %1, off sc0 sc1" : "=v"(c1) : "v"(p1) : "memory");
            // small VALU burn while retry loads are in flight (keeps DVFS up)
            #pragma unroll
            for (int z = 0; z < 8; ++z) burn = fmaf(burn, 1.000001f, 0.5f);
            asm volatile("" :: "v"(burn));
            asm volatile("s_waitcnt vmcnt(0)" ::: "memory");
            if (f0 && ((((c0[0] ^ p32) | (c0[1] ^ p32) | (c0[2] ^ p32) | (c0[3] ^ p32)) & SIGN32) == 0u)) {
                u32x4 s = {c0[0] & STRIP32, c0[1] & STRIP32, c0[2] & STRIP32, c0[3] & STRIP32};
                *(u32x4*)d0 = s; f0 = false;
            }
            if (f1 && ((((c1[0] ^ p32) | (c1[1] ^ p32) | (c1[2] ^ p32) | (c1[3] ^ p32)) & SIGN32) == 0u)) {
                u32x4 s = {c1[0] & STRIP32, c1[1] & STRIP32, c1[2] & STRIP32, c1[3] & STRIP32};
                *(u32x4*)d1 = s; f1 = false;
            }
        }
    };

    // prologue: stage h[0], barrier
    stage(0);
    __syncthreads();

    #pragma unroll 1
    for (int t = 0; t < TT; ++t) {
        // ---- MFMA: A rows r4 (M=4 dup), col icol, K=1024 from swizzled LDS ----
        f32x4 acc[4] = {{0,0,0,0},{0,0,0,0},{0,0,0,0},{0,0,0,0}};
        const char* arow = (const char*)hlds[t & 1] + r4 * 2048;
        #pragma unroll
        for (int kc = 0; kc < 32; ++kc) {
            s16x8 a0 = *(const s16x8*)(arow + (((kc << 2 | lq) ^ r4) * 16));
            acc[kc & 3] = __builtin_amdgcn_mfma_f32_16x16x32_bf16(a0, wfr[kc], acc[kc & 3], 0, 0, 0);
        }

        // ---- epilogue (valid on owner lanes lq==0: batch rows g4+r) ----
        const float phs = PH_SCALE * phv;
        const float pis = PI_SCALE * piv;
        float xn_[4], hv_[4];
        #pragma unroll
        for (int r = 0; r < 4; ++r) {
            const float rec = acc[0][r] + acc[1][r] + acc[2][r] + acc[3][r];
            float drive = 0.f;
            if (isStr) drive = (ipf[r].x + pis) * iw0 + (ipf[r].y + pis) * iw1 +
                               (ipf[r].z + pis) * iw2 + (ipf[r].w + pis) * iw3;
            const float xp = xr[r];
            const float xn = xp + DT_ * (-xp + rec + drive + inh[r]) + phs;
            const float hv = fmaxf(xn, 0.f);
            xr[r] = xn; xn_[r] = xn; hv_[r] = hv;
        }

        // ---- publish h[t+1] tagged, fire-and-forget (skip last: replay safety) ----
        if (t + 1 < TT) {
            unsigned* nxt = hbuf + (size_t)((t + 1) & 1) * 32768;
            const unsigned pn = pat32(t + 1);
            float prr[4];
            #pragma unroll
            for (int r = 0; r < 4; ++r) prr[r] = __shfl_xor(hv_[r], 1);
            if (owner && !(l15 & 1)) {
                #pragma unroll
                for (int r = 0; r < 4; ++r) {
                    const unsigned val = (((unsigned)bf16_bits(hv_[r]) |
                                           ((unsigned)bf16_bits(prr[r]) << 16)) & STRIP32);
                    __hip_atomic_store(nxt + (size_t)(g4 + r) * 512 + (icol >> 1),
                                       val | pn, __ATOMIC_RELAXED, __HIP_MEMORY_SCOPE_AGENT);
                }
            }
        }

        // ---- history stores: plain (L2-ack); acks ride under stage's vmcnt(0) ----
        if (owner) {
            #pragma unroll
            for (int r = 0; r < 4; ++r) {
                const int bi = g4 + r;
                const size_t o = ((size_t)bi * TT + t) * HH2 + icol;
                rnn_out[o] = hv_[r];
                x_out[o]   = xn_[r];
            }
        }

        // ---- next-step input prefetch ----
        const int tn = (t + 1 < TT) ? (t + 1) : t;
        #pragma unroll
        for (int r = 0; r < 4; ++r)
            ipf[r] = *(const float4*)(inp + ((size_t)(g4 + r) * TT + tn) * 4);
        phv = ph[tn]; piv = pig[tn];

        // ---- stage h[t+1] (poll+load combined), then the ONE barrier ----
        if (t + 1 < TT) stage(t + 1);
        __syncthreads();
    }
}

// ---------------- fc1: out[b,t] = dot(rnn_out[b,t,512:1024], fc1_w[512:1024]) + fc1_b ----------------
__global__ __launch_bounds__(256) void fc1_kernel(
    const float* __restrict__ rnn_out, const float* __restrict__ fc1_w,
    const float* __restrict__ fc1_b, float* __restrict__ out)
{
    const int wid = blockIdx.x * 4 + (threadIdx.x >> 6);  // [0, 64000)
    const int lane = threadIdx.x & 63;
    const float* p = rnn_out + (size_t)wid * HH2 + HH + lane * 8;
    const float* w = fc1_w + HH + lane * 8;
    f32x4 v0 = *(const f32x4*)(p);
    f32x4 v1 = *(const f32x4*)(p + 4);
    f32x4 w0 = *(const f32x4*)(w);
    f32x4 w1 = *(const f32x4*)(w + 4);
    float s = v0[0]*w0[0] + v0[1]*w0[1] + v0[2]*w0[2] + v0[3]*w0[3]
            + v1[0]*w1[0] + v1[1]*w1[1] + v1[2]*w1[2] + v1[3]*w1[3];
    #pragma unroll
    for (int off = 32; off; off >>= 1) s += __shfl_xor(s, off);
    if (lane == 0) out[wid] = s + fc1_b[0];
}

// ---------------- last-state extraction ----------------
__global__ __launch_bounds__(256) void last_kernel(
    const float* __restrict__ rnn_out, const float* __restrict__ x_out,
    float* __restrict__ hn_last, float* __restrict__ x_last)
{
    const int idx = blockIdx.x * 256 + threadIdx.x;  // [0, 65536)
    const int b = idx >> 10;
    const int i = idx & 1023;
    const size_t o = ((size_t)b * TT + (TT - 1)) * HH2 + i;
    hn_last[idx] = rnn_out[o];
    x_last[idx]  = x_out[o];
}

extern "C" void kernel_launch(void* const* d_in, const int* in_sizes, int n_in,
                              void* d_out, int out_size, void* d_ws, size_t ws_size,
                              hipStream_t stream) {
    const float* inp   = (const float*)d_in[0];   // [64,1000,4]
    const float* hn    = (const float*)d_in[1];   // [1,64,1024]
    const float* x     = (const float*)d_in[2];   // [1,64,1024]
    const float* inhib = (const float*)d_in[3];   // [64,1024]
    const float* ph    = (const float*)d_in[4];   // [1000]
    const float* pi    = (const float*)d_in[5];   // [1000]
    const float* s2s   = (const float*)d_in[6];   // [512,512]
    const float* a2a   = (const float*)d_in[7];
    const float* a2s   = (const float*)d_in[8];
    const float* s2a   = (const float*)d_in[9];
    const float* iw    = (const float*)d_in[10];  // [4,1024]
    const float* fw    = (const float*)d_in[11];  // [1,1024]
    const float* fb    = (const float*)d_in[12];  // [1]

    // Output tuple layout (floats): out | hn_last | rnn_out | x_last | x_out
    float* out     = (float*)d_out;               // 64000
    float* hn_last = out + 64000;                 // 65536
    float* rnn_out = out + 129536;                // 65,536,000
    float* x_last  = out + 65665536;              // 65536
    float* x_out   = out + 65731072;              // 65,536,000

    // Workspace: hbuf [2][64][512] u32 = 256 KB. No init needed: generation tags
    // self-disambiguate against both 0xAA poison and previous-replay residue.
    unsigned* hbuf = (unsigned*)d_ws;

    rnn_persistent<<<256, 256, 0, stream>>>(inp, hn, x, inhib, ph, pi,
                                            s2s, a2a, a2s, s2a, iw,
                                            rnn_out, x_out, hbuf);
    fc1_kernel<<<16000, 256, 0, stream>>>(rnn_out, fw, fb, out);
    last_kernel<<<256, 256, 0, stream>>>(rnn_out, x_out, hn_last, x_last);
}

// Round 15
// 2067.704 us; speedup vs baseline: 2.6649x; 1.0246x over previous
//
#include <hip/hip_runtime.h>
#include <hip/hip_bf16.h>

#define TT 1000
#define HH 512
#define HH2 1024
#define DT_ 0.01f
// sqrt(2*DT*SIGMA_RECUR^2), sqrt(2*DT*SIGMA_INPUT^2)
#define PH_SCALE 7.0710678118654745e-4f
#define PI_SCALE 7.0710678118654745e-3f

typedef short s16x8 __attribute__((ext_vector_type(8)));
typedef float f32x4 __attribute__((ext_vector_type(4)));
typedef unsigned u32x4 __attribute__((ext_vector_type(4)));

#define SIGN32  0x80008000u
#define STRIP32 0x7fff7fffu

static __device__ __forceinline__ unsigned short bf16_bits(float f) {
    union { __hip_bfloat16 h; unsigned short u; } b; b.h = __float2bfloat16(f); return b.u;
}
// generation tag for h[t]: 2 bits, period 4; same-slot reuse distance 2 -> adjacent
// generations always differ. End-of-run slots hold tags 3/2 and 0xAA poison reads
// tag 3, while t=0/1 expect tag 0 -> stale data never satisfies a poll. (R6-R14.)
static __device__ __forceinline__ unsigned pat32(int t) {
    const unsigned tg = ((unsigned)t >> 1) & 3u;
    return ((tg & 1u) << 15) | ((tg & 2u) << 30);
}

// Persistent RNN — R14 structure with a conflict-free LDS layout.
// Grid: 256 blocks x 256 threads (4 waves). Group = 16 blocks owning batch rows
// [4g, 4g+4); block = 64 cols (4 waves x 16). Wave computes a 16x16 C tile with
// M=4 duplication (A row = l15&3; owner lanes lq==0 hold batch rows r=0..3).
// LDS layout: chunk (row, X) at byte (X*4+row)*16 (16-B row interleave). A wave's
// ds_read_b128 for fixed kc covers 256 CONSECUTIVE bytes (16 distinct chunks,
// every bank exactly 2x = free) — fixes R14's 131M bank-conflict cycles caused by
// the 2048-B row stride (rows bank-aliased, ~4-way serialization).
// Protocol unchanged (R10/R13/R14): tag-in-data, publish fire-and-forget, stage-
// with-retry IS the readiness detection (write-on-pass, split vmcnt), plain
// history stores under the stage vmcnt, skip-last-publish replay safety, dbuf
// LDS, ONE __syncthreads per step, FMA burn in the retry spin.
__global__ __launch_bounds__(256, 1) void rnn_persistent(
    const float* __restrict__ inp, const float* __restrict__ hn,
    const float* __restrict__ x0g, const float* __restrict__ inhib,
    const float* __restrict__ ph, const float* __restrict__ pig,
    const float* __restrict__ s2s, const float* __restrict__ a2a,
    const float* __restrict__ a2s, const float* __restrict__ s2a,
    const float* __restrict__ iw,
    float* __restrict__ rnn_out, float* __restrict__ x_out,
    unsigned* __restrict__ hbuf)         // [2][64][512] u32 (packed tagged bf16 pairs)
{
    const int tid  = threadIdx.x;
    const int wid  = tid >> 6;
    const int lane = tid & 63;
    const int b    = blockIdx.x;         // 0..255
    const int g    = b >> 4;             // row group (batch rows 4g..4g+4)
    const int qb   = b & 15;             // block within group (64-col slice)
    const int l15  = lane & 15;
    const int lq   = lane >> 4;
    const int r4   = l15 & 3;            // A-fragment batch-row offset (M=4 dup)
    const int g4   = g * 4;
    const int icol = (qb * 4 + wid) * 16 + l15;   // output column (= W row)
    const bool owner = (lq == 0);                 // holds batch rows r=0..3

    __shared__ __align__(16) unsigned short hlds[2][4 * 1024];  // 2 x 8 KB

    // ---- publish h0 FIRST (tag gen 0) ----
    {
        float h0v[4];
        #pragma unroll
        for (int r = 0; r < 4; ++r)
            h0v[r] = hn[(size_t)(g4 + r) * HH2 + icol];
        float prr[4];
        #pragma unroll
        for (int r = 0; r < 4; ++r) prr[r] = __shfl_xor(h0v[r], 1);
        if (owner && !(l15 & 1)) {
            const unsigned p0 = pat32(0);
            #pragma unroll
            for (int r = 0; r < 4; ++r) {
                const unsigned val = (((unsigned)bf16_bits(h0v[r]) |
                                       ((unsigned)bf16_bits(prr[r]) << 16)) & STRIP32);
                __hip_atomic_store(hbuf + (size_t)(g4 + r) * 512 + (icol >> 1),
                                   val | p0, __ATOMIC_RELAXED, __HIP_MEMORY_SCOPE_AGENT);
            }
        }
    }

    // ---- W fragments in registers (one-time, f32 -> bf16) ----
    s16x8 wfr[32];
    #pragma unroll
    for (int kc = 0; kc < 32; ++kc) {
        const int j = kc * 32 + lq * 8;
        const float* src;
        if (icol < HH) src = (j < HH) ? (s2s + (size_t)icol * HH + j)
                                      : (a2s + (size_t)icol * HH + (j - HH));
        else           src = (j < HH) ? (s2a + (size_t)(icol - HH) * HH + j)
                                      : (a2a + (size_t)(icol - HH) * HH + (j - HH));
        const float4 f0 = *(const float4*)(src);
        const float4 f1 = *(const float4*)(src + 4);
        union { s16x8 vv; unsigned short us[8]; } u;
        u.us[0] = bf16_bits(f0.x); u.us[1] = bf16_bits(f0.y);
        u.us[2] = bf16_bits(f0.z); u.us[3] = bf16_bits(f0.w);
        u.us[4] = bf16_bits(f1.x); u.us[5] = bf16_bits(f1.y);
        u.us[6] = bf16_bits(f1.z); u.us[7] = bf16_bits(f1.w);
        wfr[kc] = u.vv;
    }

    // ---- register-resident epilogue state (rows g4..g4+3, uniform across lq) ----
    const bool isStr = (icol < HH);
    float iw0 = 0.f, iw1 = 0.f, iw2 = 0.f, iw3 = 0.f;
    if (isStr) {
        iw0 = iw[icol]; iw1 = iw[HH2 + icol];
        iw2 = iw[2 * HH2 + icol]; iw3 = iw[3 * HH2 + icol];
    }
    float xr[4], inh[4];
    float4 ipf[4];
    #pragma unroll
    for (int r = 0; r < 4; ++r) {
        const int bi = g4 + r;
        xr[r]  = x0g[(size_t)bi * HH2 + icol];
        inh[r] = inhib[(size_t)bi * HH2 + icol];
        ipf[r] = *(const float4*)(inp + ((size_t)bi * TT + 0) * 4);
    }
    float phv = ph[0], piv = pig[0];

    // ---- stage-with-retry of generation t into hlds[t&1] ----
    // LDS dst for chunk (row, c16) = byte (c16*4 + row)*16. Split vmcnt so chunk0's
    // check/write overlaps chunk1's flight; chunks written the moment they pass.
    auto stage = [&](int t) {
        const unsigned* srcs = hbuf + (size_t)(t & 1) * 32768 + (size_t)g4 * 512;
        char* dst = (char*)hlds[t & 1];
        const unsigned p32 = pat32(t);
        const int row0 = tid >> 7,         c160 = tid & 127;
        const int row1 = (tid + 256) >> 7, c161 = tid & 127;   // rows 0/1 then 2/3
        const unsigned* p0 = srcs + row0 * 512 + c160 * 4;
        const unsigned* p1 = srcs + row1 * 512 + c161 * 4;
        char* d0 = dst + (c160 * 4 + row0) * 16;
        char* d1 = dst + (c161 * 4 + row1) * 16;
        u32x4 c0, c1;
        asm volatile("global_load_dwordx4 %0, %1, off sc0 sc1" : "=v"(c0) : "v"(p0) : "memory");
        asm volatile("global_load_dwordx4 %0, %1, off sc0 sc1" : "=v"(c1) : "v"(p1) : "memory");
        asm volatile("s_waitcnt vmcnt(1)" ::: "memory");
        bool f0 = (((c0[0] ^ p32) | (c0[1] ^ p32) | (c0[2] ^ p32) | (c0[3] ^ p32)) & SIGN32) != 0u;
        if (!f0) { u32x4 s = {c0[0] & STRIP32, c0[1] & STRIP32, c0[2] & STRIP32, c0[3] & STRIP32};
                   *(u32x4*)d0 = s; }
        asm volatile("s_waitcnt vmcnt(0)" ::: "memory");   // also drains publish+history
        bool f1 = (((c1[0] ^ p32) | (c1[1] ^ p32) | (c1[2] ^ p32) | (c1[3] ^ p32)) & SIGN32) != 0u;
        if (!f1) { u32x4 s = {c1[0] & STRIP32, c1[1] & STRIP32, c1[2] & STRIP32, c1[3] & STRIP32};
                   *(u32x4*)d1 = s; }
        float burn = (float)tid;
        while (f0 || f1) {
            if (f0) asm volatile("global_load_dwordx4 %0, %1, off sc0 sc1" : "=v"(c0) : "v"(p0) : "memory");
            if (f1) asm volatile("global_load_dwordx4 %0, %1, off sc0 sc1" : "=v"(c1) : "v"(p1) : "memory");
            // small VALU burn while retry loads are in flight (keeps DVFS up)
            #pragma unroll
            for (int z = 0; z < 8; ++z) burn = fmaf(burn, 1.000001f, 0.5f);
            asm volatile("" :: "v"(burn));
            asm volatile("s_waitcnt vmcnt(0)" ::: "memory");
            if (f0 && ((((c0[0] ^ p32) | (c0[1] ^ p32) | (c0[2] ^ p32) | (c0[3] ^ p32)) & SIGN32) == 0u)) {
                u32x4 s = {c0[0] & STRIP32, c0[1] & STRIP32, c0[2] & STRIP32, c0[3] & STRIP32};
                *(u32x4*)d0 = s; f0 = false;
            }
            if (f1 && ((((c1[0] ^ p32) | (c1[1] ^ p32) | (c1[2] ^ p32) | (c1[3] ^ p32)) & SIGN32) == 0u)) {
                u32x4 s = {c1[0] & STRIP32, c1[1] & STRIP32, c1[2] & STRIP32, c1[3] & STRIP32};
                *(u32x4*)d1 = s; f1 = false;
            }
        }
    };

    // prologue: stage h[0], barrier
    stage(0);
    __syncthreads();

    #pragma unroll 1
    for (int t = 0; t < TT; ++t) {
        // ---- MFMA: A rows r4 (M=4 dup), col icol, K=1024. Read at byte
        //      kc*256 + (lq*4 + r4)*16: 16 distinct chunks = 256 consecutive
        //      bytes per kc -> every bank exactly 2x (free). ----
        f32x4 acc[4] = {{0,0,0,0},{0,0,0,0},{0,0,0,0},{0,0,0,0}};
        const char* arow = (const char*)hlds[t & 1] + (lq * 4 + r4) * 16;
        #pragma unroll
        for (int kc = 0; kc < 32; ++kc) {
            s16x8 a0 = *(const s16x8*)(arow + kc * 256);
            acc[kc & 3] = __builtin_amdgcn_mfma_f32_16x16x32_bf16(a0, wfr[kc], acc[kc & 3], 0, 0, 0);
        }

        // ---- epilogue (valid on owner lanes lq==0: batch rows g4+r) ----
        const float phs = PH_SCALE * phv;
        const float pis = PI_SCALE * piv;
        float xn_[4], hv_[4];
        #pragma unroll
        for (int r = 0; r < 4; ++r) {
            const float rec = acc[0][r] + acc[1][r] + acc[2][r] + acc[3][r];
            float drive = 0.f;
            if (isStr) drive = (ipf[r].x + pis) * iw0 + (ipf[r].y + pis) * iw1 +
                               (ipf[r].z + pis) * iw2 + (ipf[r].w + pis) * iw3;
            const float xp = xr[r];
            const float xn = xp + DT_ * (-xp + rec + drive + inh[r]) + phs;
            const float hv = fmaxf(xn, 0.f);
            xr[r] = xn; xn_[r] = xn; hv_[r] = hv;
        }

        // ---- publish h[t+1] tagged, fire-and-forget (skip last: replay safety) ----
        if (t + 1 < TT) {
            unsigned* nxt = hbuf + (size_t)((t + 1) & 1) * 32768;
            const unsigned pn = pat32(t + 1);
            float prr[4];
            #pragma unroll
            for (int r = 0; r < 4; ++r) prr[r] = __shfl_xor(hv_[r], 1);
            if (owner && !(l15 & 1)) {
                #pragma unroll
                for (int r = 0; r < 4; ++r) {
                    const unsigned val = (((unsigned)bf16_bits(hv_[r]) |
                                           ((unsigned)bf16_bits(prr[r]) << 16)) & STRIP32);
                    __hip_atomic_store(nxt + (size_t)(g4 + r) * 512 + (icol >> 1),
                                       val | pn, __ATOMIC_RELAXED, __HIP_MEMORY_SCOPE_AGENT);
                }
            }
        }

        // ---- history stores: plain (L2-ack); acks ride under stage's vmcnt(0) ----
        if (owner) {
            #pragma unroll
            for (int r = 0; r < 4; ++r) {
                const int bi = g4 + r;
                const size_t o = ((size_t)bi * TT + t) * HH2 + icol;
                rnn_out[o] = hv_[r];
                x_out[o]   = xn_[r];
            }
        }

        // ---- next-step input prefetch ----
        const int tn = (t + 1 < TT) ? (t + 1) : t;
        #pragma unroll
        for (int r = 0; r < 4; ++r)
            ipf[r] = *(const float4*)(inp + ((size_t)(g4 + r) * TT + tn) * 4);
        phv = ph[tn]; piv = pig[tn];

        // ---- stage h[t+1] (poll+load combined), then the ONE barrier ----
        if (t + 1 < TT) stage(t + 1);
        __syncthreads();
    }
}

// ---------------- fc1: out[b,t] = dot(rnn_out[b,t,512:1024], fc1_w[512:1024]) + fc1_b ----------------
__global__ __launch_bounds__(256) void fc1_kernel(
    const float* __restrict__ rnn_out, const float* __restrict__ fc1_w,
    const float* __restrict__ fc1_b, float* __restrict__ out)
{
    const int wid = blockIdx.x * 4 + (threadIdx.x >> 6);  // [0, 64000)
    const int lane = threadIdx.x & 63;
    const float* p = rnn_out + (size_t)wid * HH2 + HH + lane * 8;
    const float* w = fc1_w + HH + lane * 8;
    f32x4 v0 = *(const f32x4*)(p);
    f32x4 v1 = *(const f32x4*)(p + 4);
    f32x4 w0 = *(const f32x4*)(w);
    f32x4 w1 = *(const f32x4*)(w + 4);
    float s = v0[0]*w0[0] + v0[1]*w0[1] + v0[2]*w0[2] + v0[3]*w0[3]
            + v1[0]*w1[0] + v1[1]*w1[1] + v1[2]*w1[2] + v1[3]*w1[3];
    #pragma unroll
    for (int off = 32; off; off >>= 1) s += __shfl_xor(s, off);
    if (lane == 0) out[wid] = s + fc1_b[0];
}

// ---------------- last-state extraction ----------------
__global__ __launch_bounds__(256) void last_kernel(
    const float* __restrict__ rnn_out, const float* __restrict__ x_out,
    float* __restrict__ hn_last, float* __restrict__ x_last)
{
    const int idx = blockIdx.x * 256 + threadIdx.x;  // [0, 65536)
    const int b = idx >> 10;
    const int i = idx & 1023;
    const size_t o = ((size_t)b * TT + (TT - 1)) * HH2 + i;
    hn_last[idx] = rnn_out[o];
    x_last[idx]  = x_out[o];
}

extern "C" void kernel_launch(void* const* d_in, const int* in_sizes, int n_in,
                              void* d_out, int out_size, void* d_ws, size_t ws_size,
                              hipStream_t stream) {
    const float* inp   = (const float*)d_in[0];   // [64,1000,4]
    const float* hn    = (const float*)d_in[1];   // [1,64,1024]
    const float* x     = (const float*)d_in[2];   // [1,64,1024]
    const float* inhib = (const float*)d_in[3];   // [64,1024]
    const float* ph    = (const float*)d_in[4];   // [1000]
    const float* pi    = (const float*)d_in[5];   // [1000]
    const float* s2s   = (const float*)d_in[6];   // [512,512]
    const float* a2a   = (const float*)d_in[7];
    const float* a2s   = (const float*)d_in[8];
    const float* s2a   = (const float*)d_in[9];
    const float* iw    = (const float*)d_in[10];  // [4,1024]
    const float* fw    = (const float*)d_in[11];  // [1,1024]
    const float* fb    = (const float*)d_in[12];  // [1]

    // Output tuple layout (floats): out | hn_last | rnn_out | x_last | x_out
    float* out     = (float*)d_out;               // 64000
    float* hn_last = out + 64000;                 // 65536
    float* rnn_out = out + 129536;                // 65,536,000
    float* x_last  = out + 65665536;              // 65536
    float* x_out   = out + 65731072;              // 65,536,000

    // Workspace: hbuf [2][64][512] u32 = 256 KB. No init needed: generation tags
    // self-disambiguate against both 0xAA poison and previous-replay residue.
    unsigned* hbuf = (unsigned*)d_ws;

    rnn_persistent<<<256, 256, 0, stream>>>(inp, hn, x, inhib, ph, pi,
                                            s2s, a2a, a2s, s2a, iw,
                                            rnn_out, x_out, hbuf);
    fc1_kernel<<<16000, 256, 0, stream>>>(rnn_out, fw, fb, out);
    last_kernel<<<256, 256, 0, stream>>>(rnn_out, x_out, hn_last, x_last);
}